// Round 7
// baseline (3167.021 us; speedup 1.0000x reference)
//
#include <hip/hip_runtime.h>
#include <hip/hip_bf16.h>

#define Bsz 128
#define Tsz 1024
#define Dsz 128
#define Hsz 512
#define NBLK 256
#define NKC 20  // 640 / 32 K-chunks

typedef __attribute__((ext_vector_type(8))) short short8;
typedef __attribute__((ext_vector_type(4))) float f4;
typedef unsigned long long u64;

__device__ __forceinline__ short bf16_rne(float f) {
  unsigned u = __builtin_bit_cast(unsigned, f);
  u += 0x7fffu + ((u >> 16) & 1u);
  return (short)(u >> 16);
}
__device__ __forceinline__ float sigmoid_(float v) { return 1.f / (1.f + __expf(-v)); }
// tanh(x) = 1 - 2/(e^{2x}+1); saturates correctly for |x| large (exp->0 or inf)
__device__ __forceinline__ float tanh_fast(float v) {
  return 1.f - 2.f / (1.f + __expf(2.f * v));
}

// Persistent LSTM. LLC exchange protocol = EXACT 3146us anchor (r6): all-wave
// sleep-poll of 32 block flags, A_lds staging, barrier 1, trailing barrier +
// tx0 flag store. r1-r4 protocol variants all regressed; protocol is frozen.
//
// Round-7 delta (intra-block only): per-wave gate layout + shfl combine.
//  - B-operand remap: output col n of wave w = gate (n>>2), h-col k0+w*4+(n&3).
//    So one wave computes i,f,g,o for its own 4 h-cols x 16 rows.
//  - After the K loop, a 4x4 in-register transpose over (lane bits[3:2] <->
//    reg index) via 8 shfl_xor(4/8) + selects puts {i,f,g,o} of one (row,col)
//    into one lane. Combine + c/h update is then lane-local.
//  - gates_lds and barrier 2 are DELETED (3 barriers/step -> 2); h stores
//    issue immediately after the MFMA sum. h packed as u64 per 4 cols.
__global__ __launch_bounds__(256, 1) void lstm_persist(
    const float* __restrict__ x, const float* __restrict__ W_ih,
    const float* __restrict__ W_hh, const float* __restrict__ b_ih,
    const float* __restrict__ b_hh, const float* __restrict__ W_fc,
    const float* __restrict__ b_fc, float* __restrict__ out,
    int* flags, unsigned short* hb0, unsigned short* hb1)
{
  const int bx = blockIdx.x;
  const int bt = bx & 7, ks = bx >> 3;   // group = same bt (same XCD if round-robin)
  const int b0 = bt << 4, k0 = ks << 4;
  const int tx = threadIdx.x;
  const int wave = tx >> 6, lane = tx & 63;
  const int m = lane & 15, quad = lane >> 4;
  const int k_l = tx & 15, b_l = tx >> 4;   // FC-tail ownership

  __shared__ short8 A_lds[NKC][64];      // 20 KB, pre-permuted A fragments
  __shared__ float fc_red[16][16];       // final FC reduction

  int* gflags = flags + bt * 32;         // 32 flags = 128 B, one group

  // ---- load W fragments into registers (once). ----
  // Output col n: gate g = n>>2, h-col = k0 + wave*4 + (n&3).
  const int mycol = k0 + wave * 4 + (m & 3);
  short8 wfrag[NKC];
  {
    const int j = (m >> 2) * Hsz + mycol;  // W row for output col n=m
    #pragma unroll
    for (int kc = 0; kc < NKC; ++kc) {
      const int kk = kc * 32 + quad * 8;
      const float* src = (kk < Dsz) ? (W_ih + (size_t)j * Dsz + kk)
                                    : (W_hh + (size_t)j * Hsz + (kk - Dsz));
      const f4* sv = (const f4*)src;
      f4 v0 = sv[0], v1 = sv[1];
      short8 w;
      w[0] = bf16_rne(v0[0]); w[1] = bf16_rne(v0[1]);
      w[2] = bf16_rne(v0[2]); w[3] = bf16_rne(v0[3]);
      w[4] = bf16_rne(v1[0]); w[5] = bf16_rne(v1[1]);
      w[6] = bf16_rne(v1[2]); w[7] = bf16_rne(v1[3]);
      wfrag[kc] = w;
    }
  }
  float bias[4];
  #pragma unroll
  for (int g = 0; g < 4; ++g)
    bias[g] = b_ih[g * Hsz + mycol] + b_hh[g * Hsz + mycol];
  float c_reg = 0.f;   // this lane owns (row = quad*4 + (m>>2), col = mycol)

  for (int t = 0; t < Tsz; ++t) {
    unsigned short* hnext = (t & 1) ? hb1 : hb0;
    const unsigned short* hprev = (t & 1) ? hb0 : hb1;

    // Issue x loads first: in flight (normal, L2-cached) while we poll.
    const f4* xv = (const f4*)(x + (size_t)(b0 + m) * (Tsz * Dsz)
                               + (size_t)t * Dsz + wave * 32 + quad * 8);
    f4 v0 = xv[0], v1 = xv[1];

    if (t > 0) {
      // all 4 waves poll the 32 group flags (lanes 32..63 mirror 0..31)
      for (;;) {
        int f = __hip_atomic_load(gflags + (lane & 31),
                                  __ATOMIC_RELAXED, __HIP_MEMORY_SCOPE_AGENT);
        if (__all(f >= t)) break;
        __builtin_amdgcn_s_sleep(1);
      }
      // stage this wave's 4 h chunks from LLC (agent-scope loads, bypass L2)
      #pragma unroll
      for (int q = 0; q < 4; ++q) {
        const int kc = 4 + wave * 4 + q;
        const int kh = (kc - 4) * 32 + quad * 8;
        const u64* p = (const u64*)(hprev + (size_t)(b0 + m) * Hsz + kh);
        u64 lo = __hip_atomic_load(p,     __ATOMIC_RELAXED, __HIP_MEMORY_SCOPE_AGENT);
        u64 hi = __hip_atomic_load(p + 1, __ATOMIC_RELAXED, __HIP_MEMORY_SCOPE_AGENT);
        u64* dst = (u64*)&A_lds[kc][lane];
        dst[0] = lo; dst[1] = hi;
      }
    } else {
      short8 z = {0, 0, 0, 0, 0, 0, 0, 0};
      #pragma unroll
      for (int q = 0; q < 4; ++q) A_lds[4 + wave * 4 + q][lane] = z;
    }

    { // stage x chunk (kc = wave, K 0..127)
      short8 a;
      a[0] = bf16_rne(v0[0]); a[1] = bf16_rne(v0[1]);
      a[2] = bf16_rne(v0[2]); a[3] = bf16_rne(v0[3]);
      a[4] = bf16_rne(v1[0]); a[5] = bf16_rne(v1[1]);
      a[6] = bf16_rne(v1[2]); a[7] = bf16_rne(v1[3]);
      A_lds[wave][lane] = a;
    }
    __syncthreads();   // barrier 1: A_lds complete before any wave's MFMA reads

    // ---- K loop: 20 x (ds_read_b128 + mfma), 4 accumulators for ILP
    f4 a0 = {0.f, 0.f, 0.f, 0.f}, a1 = {0.f, 0.f, 0.f, 0.f};
    f4 a2 = {0.f, 0.f, 0.f, 0.f}, a3 = {0.f, 0.f, 0.f, 0.f};
    #pragma unroll
    for (int kc = 0; kc < NKC; kc += 4) {
      a0 = __builtin_amdgcn_mfma_f32_16x16x32_bf16(A_lds[kc][lane],     wfrag[kc],     a0, 0, 0, 0);
      a1 = __builtin_amdgcn_mfma_f32_16x16x32_bf16(A_lds[kc + 1][lane], wfrag[kc + 1], a1, 0, 0, 0);
      a2 = __builtin_amdgcn_mfma_f32_16x16x32_bf16(A_lds[kc + 2][lane], wfrag[kc + 2], a2, 0, 0, 0);
      a3 = __builtin_amdgcn_mfma_f32_16x16x32_bf16(A_lds[kc + 3][lane], wfrag[kc + 3], a3, 0, 0, 0);
    }
    f4 acc = (a0 + a1) + (a2 + a3);  // lane: D[row=quad*4+r][n=m], n=(gate,col)

    { // ---- 4x4 transpose over (lane bits[3:2] <-> reg idx), then combine ----
      const int g0b = (m >> 2) & 1, g1b = (m >> 3) & 1;
      // stage 1: swap G bit0 with reg bit0 (dist 4)
      float s1[4], v1[4];
      #pragma unroll
      for (int r = 0; r < 4; ++r) s1[r] = __shfl_xor(acc[r ^ 1], 4);
      #pragma unroll
      for (int r = 0; r < 4; ++r) v1[r] = ((r & 1) == g0b) ? acc[r] : s1[r];
      // stage 2: swap G bit1 with reg bit1 (dist 8)
      float s2[4], v2[4];
      #pragma unroll
      for (int r = 0; r < 4; ++r) s2[r] = __shfl_xor(v1[r ^ 2], 8);
      #pragma unroll
      for (int r = 0; r < 4; ++r) v2[r] = (((r >> 1) & 1) == g1b) ? v1[r] : s2[r];
      // now v2[g] = gate g pre-activation for (row = quad*4 + (m>>2), col = mycol)
      float pi = v2[0] + bias[0];
      float pf = v2[1] + bias[1];
      float pg = v2[2] + bias[2];
      float po = v2[3] + bias[3];
      float iv = sigmoid_(pi), fv = sigmoid_(pf), ov = sigmoid_(po);
      float gv = tanh_fast(pg);
      c_reg = fv * c_reg + iv * gv;
      float hv = ov * tanh_fast(c_reg);
      // pack 4 cols (this wave's col group) into one u64 store per (row)
      unsigned hbits = (unsigned)(unsigned short)bf16_rne(hv);
      unsigned lo = hbits | (__shfl_xor(hbits, 1) << 16);  // cols c, c^1
      u64 both = ((u64)__shfl_xor(lo, 2) << 32) | (u64)lo; // + cols c^2, c^3
      if ((m & 3) == 0) {
        const int brow = b0 + quad * 4 + (m >> 2);
        u64* p = (u64*)(hnext + (size_t)brow * Hsz + k0 + wave * 4);
        __hip_atomic_store(p, both, __ATOMIC_RELAXED, __HIP_MEMORY_SCOPE_AGENT);
      }
    }
    __syncthreads();               // drains vmcnt: all waves' h stores at LLC
    if (tx == 0)
      __hip_atomic_store(gflags + ks, t + 1, __ATOMIC_RELAXED, __HIP_MEMORY_SCOPE_AGENT);
  }

  // ---- final FC: out[b] = sigmoid(h_last . W_fc + b_fc), ks==0 blocks ----
  if (ks == 0) {
    for (;;) {
      int f = __hip_atomic_load(gflags + (lane & 31),
                                __ATOMIC_RELAXED, __HIP_MEMORY_SCOPE_AGENT);
      if (__all(f >= Tsz)) break;
      __builtin_amdgcn_s_sleep(1);
    }
    const unsigned short* hl = hb1;  // t=1023 (odd) wrote hb1
    const u64* p = (const u64*)(hl + (size_t)(b0 + b_l) * Hsz + k_l * 32);
    float partial = 0.f;
    #pragma unroll
    for (int q = 0; q < 8; ++q) {
      u64 v = __hip_atomic_load(p + q, __ATOMIC_RELAXED, __HIP_MEMORY_SCOPE_AGENT);
      #pragma unroll
      for (int e = 0; e < 4; ++e) {
        unsigned hv16 = (unsigned)((v >> (16 * e)) & 0xffffu);
        partial += __builtin_bit_cast(float, hv16 << 16) * W_fc[k_l * 32 + q * 4 + e];
      }
    }
    fc_red[b_l][k_l] = partial;
    __syncthreads();
    if (k_l == 0) {
      float s = b_fc[0];
      #pragma unroll
      for (int e = 0; e < 16; ++e) s += fc_red[b_l][e];
      out[b0 + b_l] = sigmoid_(s);
    }
  }
}

extern "C" void kernel_launch(void* const* d_in, const int* in_sizes, int n_in,
                              void* d_out, int out_size, void* d_ws, size_t ws_size,
                              hipStream_t stream) {
  const float* x    = (const float*)d_in[0];
  const float* W_ih = (const float*)d_in[1];
  const float* W_hh = (const float*)d_in[2];
  const float* b_ih = (const float*)d_in[3];
  const float* b_hh = (const float*)d_in[4];
  const float* W_fc = (const float*)d_in[5];
  const float* b_fc = (const float*)d_in[6];
  float* out = (float*)d_out;
  char* ws = (char*)d_ws;
  int* flags = (int*)ws;                                   // 8 groups x 32 flags
  unsigned short* hb0 = (unsigned short*)(ws + 4096);      // h double buffer (bf16)
  unsigned short* hb1 = (unsigned short*)(ws + 4096 + (size_t)Bsz * Hsz * 2);
  hipMemsetAsync(ws, 0, 4096, stream);                     // barrier flags := 0
  lstm_persist<<<NBLK, 256, 0, stream>>>(x, W_ih, W_hh, b_ih, b_hh, W_fc, b_fc,
                                         out, flags, hb0, hb1);
}